// Round 7
// baseline (187.758 us; speedup 1.0000x reference)
//
#include <hip/hip_runtime.h>
#include <hip/hip_bf16.h>
#include <math.h>

// Flash attention, bf16 MFMA 16x16x32, fp32 accumulate. B=2,H=12,S=2048,D=64.
// R7: split-K fused into one block: 512 threads = 8 waves; waves 0-3 process
// keys [0,1024), waves 4-7 keys [1024,2048) for the same 128-q tile. Partials
// are exactly additive (exp without max subtraction); combined in LDS at the
// epilogue and stored normalized directly to O -> no reduce kernel, no Opart.
// Staging: global_load_lds w=16 into XOR-swizzled LDS; S^T MFMA order (b64 P
// writes, coalesced transposed bit-mask); row-sum l via ones-column MFMA.

#define BB 2
#define HH 12
#define SS 2048
#define DD 64
#define BQ 128
#define BK 64
#define GG 2
#define KG (SS / GG)      // 1024 keys per group
#define NTG (KG / BK)     // 16 tiles per group
#define LT 76             // prepass transpose stride
#define QSCALE 0.1803368801111f   // 0.125 * log2(e)

// LDS map (bytes): region0 [0,33280): 4 staging tiles (2 groups x K,V, 8192 B
// each, 32768 B) ALIASED with epilogue Of[128][65] floats (33280 B).
// Ps [33280,70144): 256 rows x 72 shorts. Lf [70144,70656): 128 floats.
#define TILE_B   8192
#define PS_OFF   33280
#define LP       72
#define LF_OFF   70144
#define LDS_B    70656

typedef __attribute__((ext_vector_type(8))) short bf8_t;
typedef __attribute__((ext_vector_type(4))) short bf4_t;
typedef __attribute__((ext_vector_type(4))) float f4_t;
typedef unsigned long long u64;

__device__ __forceinline__ short f2bf(float f) {
    __hip_bfloat16 h = __float2bfloat16(f);
    return *reinterpret_cast<short*>(&h);
}

__device__ __forceinline__ void gl_lds16(const void* g, void* l) {
    __builtin_amdgcn_global_load_lds(
        (const __attribute__((address_space(1))) unsigned*)(g),
        (__attribute__((address_space(3))) unsigned*)(l), 16, 0, 0);
}

// swizzled tile: element (row, c8-chunk) lives at chunk row*8 + (c8 ^ (row&7))
__device__ __forceinline__ bf8_t ldfrag(const unsigned short* buf, int row, int c8) {
    return *(const bf8_t*)&buf[((row << 3) | (c8 ^ (row & 7))) << 3];
}

// ---------- fused prepass ----------
// grid = BB*SS = 4096 blocks x 256.
//  all blocks: pack mask row -> Mbt[b][word][row] (TRANSPOSED for coalescing)
//  bx <  768 : V [bh][s][d] fp32 -> Vt [bh][d][s] bf16 (64-row tile)
//  768..2304 : K fp32 -> Kb bf16
__global__ __launch_bounds__(256) void prepass(
    const float* __restrict__ V, const float* __restrict__ K,
    const int* __restrict__ M, unsigned short* __restrict__ Vt,
    unsigned short* __restrict__ Kb, u64* __restrict__ Mbt)
{
    __shared__ unsigned short Ts[64][LT];
    const int bx   = blockIdx.x;
    const int tid  = threadIdx.x;
    const int w    = tid >> 6;
    const int lane = tid & 63;
    const int b    = bx >> 11;
    const int row  = bx & 2047;

    {   // mask row bx -> 32 words, transposed layout [b][word][row]
        const int* src = M + (size_t)bx * SS;
        #pragma unroll
        for (int p = 0; p < 8; ++p) {
            int k = p * 256 + w * 64 + lane;
            u64 bm = __ballot(src[k] != 0);
            if (lane == 0)
                Mbt[(size_t)b * 32 * SS + (size_t)(p * 4 + w) * SS + row] = bm;
        }
    }

    if (bx < 768) {
        const int s0 = (bx & 31) * 64;
        const int bh = bx >> 5;
        const float* Vg = V + (size_t)bh * SS * DD;
        #pragma unroll
        for (int pass = 0; pass < 4; ++pass) {
            int c = tid + pass * 256;
            int r = c >> 4, col = (c & 15) * 4;
            float4 v = *(const float4*)(Vg + (size_t)(s0 + r) * DD + col);
            bf4_t p; p.x = f2bf(v.x); p.y = f2bf(v.y); p.z = f2bf(v.z); p.w = f2bf(v.w);
            *(bf4_t*)&Ts[r][col] = p;
        }
        __syncthreads();
        unsigned short* Vo = Vt + (size_t)bh * DD * SS;
        #pragma unroll
        for (int pass = 0; pass < 2; ++pass) {
            int c = tid + pass * 256;
            int d = c >> 3, sc = (c & 7) * 8;
            unsigned short t[8];
            #pragma unroll
            for (int u = 0; u < 8; ++u) t[u] = Ts[sc + u][d];
            uint4 o;
            o.x = (unsigned)t[0] | ((unsigned)t[1] << 16);
            o.y = (unsigned)t[2] | ((unsigned)t[3] << 16);
            o.z = (unsigned)t[4] | ((unsigned)t[5] << 16);
            o.w = (unsigned)t[6] | ((unsigned)t[7] << 16);
            *(uint4*)(Vo + (size_t)d * SS + s0 + sc) = o;
        }
    } else if (bx < 2304) {
        size_t i = ((size_t)(bx - 768) * 256 + tid) * 8;
        float4 a = *(const float4*)(K + i);
        float4 b2 = *(const float4*)(K + i + 4);
        uint4 o;
        o.x = (unsigned short)f2bf(a.x)  | ((unsigned)(unsigned short)f2bf(a.y)  << 16);
        o.y = (unsigned short)f2bf(a.z)  | ((unsigned)(unsigned short)f2bf(a.w)  << 16);
        o.z = (unsigned short)f2bf(b2.x) | ((unsigned)(unsigned short)f2bf(b2.y) << 16);
        o.w = (unsigned short)f2bf(b2.z) | ((unsigned)(unsigned short)f2bf(b2.w) << 16);
        *(uint4*)(Kb + i) = o;
    }
}

// ---------- fused flash-attention kernel (both key groups per block) --------
__global__ __launch_bounds__(512, 4) void attn_fwd(
    const float* __restrict__ Q, const unsigned short* __restrict__ Kb,
    const unsigned short* __restrict__ Vt, const u64* __restrict__ Mbt,
    float* __restrict__ O)
{
    __shared__ __align__(16) char ls[LDS_B];

    const int tid  = threadIdx.x;
    const int w    = tid >> 6;        // 0..7
    const int g    = w >> 2;          // key group 0/1
    const int wl   = w & 3;           // wave within group
    const int lane = tid & 63;
    const int quad = lane >> 4;
    const int l16  = lane & 15;
    const int q0   = blockIdx.x * BQ;
    const int bh   = blockIdx.y;
    const int b    = bh / HH;
    const int qbase = wl * 32;        // this wave's first q row in tile

    unsigned short* tileK = (unsigned short*)(ls + g * 2 * TILE_B);
    unsigned short* tileV = (unsigned short*)(ls + g * 2 * TILE_B + TILE_B);
    unsigned short* Ps    = (unsigned short*)(ls + PS_OFF);
    float*          Of    = (float*)ls;
    float*          Lf    = (float*)(ls + LF_OFF);

    const float*          Qg = Q  + (size_t)bh * SS * DD;
    const unsigned short* Kg = Kb + (size_t)bh * SS * DD;
    const unsigned short* Vg = Vt + (size_t)bh * DD * SS;
    float*                Og = O  + (size_t)bh * SS * DD;

    // ---- loop-invariant Q B-frags (two 16-row groups), 0.125*log2e folded
    bf8_t bq[2][2];
    #pragma unroll
    for (int qf = 0; qf < 2; ++qf)
        #pragma unroll
        for (int ks = 0; ks < 2; ++ks) {
            const float* qp = Qg + (size_t)(q0 + qbase + qf * 16 + l16) * DD
                                 + ks * 32 + quad * 8;
            float4 x = *(const float4*)qp;
            float4 y = *(const float4*)(qp + 4);
            bf8_t f;
            f[0] = f2bf(x.x * QSCALE); f[1] = f2bf(x.y * QSCALE);
            f[2] = f2bf(x.z * QSCALE); f[3] = f2bf(x.w * QSCALE);
            f[4] = f2bf(y.x * QSCALE); f[5] = f2bf(y.y * QSCALE);
            f[6] = f2bf(y.z * QSCALE); f[7] = f2bf(y.w * QSCALE);
            bq[qf][ks] = f;
        }

    // ---- ones column B-frag -> row-sum l in D col 0
    bf8_t onesf;
    {
        short ov = (l16 == 0) ? (short)0x3F80 : (short)0;
        #pragma unroll
        for (int j = 0; j < 8; ++j) onesf[j] = ov;
    }

    f4_t oacc[2][4], lacc[2];
    #pragma unroll
    for (int qf = 0; qf < 2; ++qf) {
        lacc[qf] = (f4_t){0.f, 0.f, 0.f, 0.f};
        #pragma unroll
        for (int nf = 0; nf < 4; ++nf) oacc[qf][nf] = (f4_t){0.f, 0.f, 0.f, 0.f};
    }

    // ---- strength-reduced staging pointers (group g's 4 waves stage its
    // K and V tiles; 2 chunks each of 64 lanes)
    const unsigned short* kSrc[2];
    const unsigned short* vSrc[2];
    unsigned short*       kDst[2];
    unsigned short*       vDst[2];
    #pragma unroll
    for (int j = 0; j < 2; ++j) {
        const int bc = (wl * 2 + j) * 64;    // wave-uniform chunk base
        const int c  = bc + lane;
        const int r  = c >> 3;
        const int c8 = (c & 7) ^ (r & 7);
        kSrc[j] = Kg + (size_t)(g * KG + r) * DD + c8 * 8;
        vSrc[j] = Vg + (size_t)r * SS + g * KG + c8 * 8;
        kDst[j] = tileK + bc * 8;
        vDst[j] = tileV + bc * 8;
    }
    const u64* mp[2];
    u64 mpf[2];
    #pragma unroll
    for (int qf = 0; qf < 2; ++qf) {
        mp[qf] = Mbt + (size_t)b * 32 * SS + (size_t)(g * NTG) * SS
                     + q0 + qbase + qf * 16 + l16;
        mpf[qf] = *mp[qf];
    }

    for (int t = 0; t < NTG; ++t) {
        __syncthreads();                 // prior tile's LDS readers done
        #pragma unroll
        for (int j = 0; j < 2; ++j) {
            gl_lds16(kSrc[j], kDst[j]);
            gl_lds16(vSrc[j], vDst[j]);
            kSrc[j] += BK * DD;          // next K tile (rows advance by BK)
            vSrc[j] += BK;               // next V tile (cols advance by BK)
        }
        u64 cm[2] = {mpf[0] >> (quad * 4), mpf[1] >> (quad * 4)};
        __syncthreads();                 // vmcnt drained: tiles visible
        if (t + 1 < NTG) {
            #pragma unroll
            for (int qf = 0; qf < 2; ++qf) {
                mp[qf] += SS;
                mpf[qf] = *mp[qf];
            }
        }

        // ---- S^T = K_tile . Q^T : D[k][q]; K frags shared across q-frags
        f4_t sacc[4][2];
        #pragma unroll
        for (int kf = 0; kf < 4; ++kf) {
            bf8_t ak0 = ldfrag(tileK, kf * 16 + l16, quad);
            bf8_t ak1 = ldfrag(tileK, kf * 16 + l16, 4 + quad);
            #pragma unroll
            for (int qf = 0; qf < 2; ++qf) {
                f4_t a = (f4_t){0.f, 0.f, 0.f, 0.f};
                a = __builtin_amdgcn_mfma_f32_16x16x32_bf16(ak0, bq[qf][0], a, 0, 0, 0);
                a = __builtin_amdgcn_mfma_f32_16x16x32_bf16(ak1, bq[qf][1], a, 0, 0, 0);
                sacc[kf][qf] = a;
            }
        }

        // ---- masked exp2; lane holds k = kf*16+quad*4+r for q = qf*16+l16
        #pragma unroll
        for (int qf = 0; qf < 2; ++qf) {
            const int prow = w * 32 + qf * 16 + l16;
            #pragma unroll
            for (int kf = 0; kf < 4; ++kf) {
                bf4_t pk;
                #pragma unroll
                for (int r = 0; r < 4; ++r) {
                    float e = exp2f(sacc[kf][qf][r]);
                    e = ((cm[qf] >> (kf * 16 + r)) & 1ull) ? e : 0.f;
                    pk[r] = f2bf(e);
                }
                *(bf4_t*)&Ps[prow * LP + kf * 16 + quad * 4] = pk;
            }
        }

        // ---- P A-frags (wave-private rows; in-order LDS: no barrier)
        bf8_t ap[2][2];
        #pragma unroll
        for (int qf = 0; qf < 2; ++qf) {
            const int prow = w * 32 + qf * 16 + l16;
            ap[qf][0] = *(const bf8_t*)&Ps[prow * LP + quad * 8];
            ap[qf][1] = *(const bf8_t*)&Ps[prow * LP + 32 + quad * 8];
            lacc[qf] = __builtin_amdgcn_mfma_f32_16x16x32_bf16(ap[qf][0], onesf, lacc[qf], 0, 0, 0);
            lacc[qf] = __builtin_amdgcn_mfma_f32_16x16x32_bf16(ap[qf][1], onesf, lacc[qf], 0, 0, 0);
        }

        // ---- PV; V frags shared across q-frags
        #pragma unroll
        for (int nf = 0; nf < 4; ++nf) {
            bf8_t bv0 = ldfrag(tileV, nf * 16 + l16, quad);
            bf8_t bv1 = ldfrag(tileV, nf * 16 + l16, 4 + quad);
            #pragma unroll
            for (int qf = 0; qf < 2; ++qf) {
                oacc[qf][nf] = __builtin_amdgcn_mfma_f32_16x16x32_bf16(ap[qf][0], bv0, oacc[qf][nf], 0, 0, 0);
                oacc[qf][nf] = __builtin_amdgcn_mfma_f32_16x16x32_bf16(ap[qf][1], bv1, oacc[qf][nf], 0, 0, 0);
            }
        }
    }

    // ---- epilogue: combine the two key-groups in LDS, normalize, store
    __syncthreads();                     // all K-loop LDS reads complete
    if (g == 1) {
        #pragma unroll
        for (int qf = 0; qf < 2; ++qf) {
            #pragma unroll
            for (int r = 0; r < 4; ++r) {
                const int row = qbase + qf * 16 + quad * 4 + r;
                #pragma unroll
                for (int nf = 0; nf < 4; ++nf)
                    Of[row * 65 + nf * 16 + l16] = oacc[qf][nf][r];
            }
            if (l16 == 0) {
                #pragma unroll
                for (int r = 0; r < 4; ++r)
                    Lf[qbase + qf * 16 + quad * 4 + r] = lacc[qf][r];
            }
        }
    }
    __syncthreads();
    if (g == 0) {
        #pragma unroll
        for (int qf = 0; qf < 2; ++qf)
            #pragma unroll
            for (int r = 0; r < 4; ++r) {
                const int row = qbase + qf * 16 + quad * 4 + r;
                const float l0 = __shfl(lacc[qf][r], lane & 48);
                const float inv = 1.f / (l0 + Lf[row]);
                #pragma unroll
                for (int nf = 0; nf < 4; ++nf)
                    Og[(size_t)(q0 + row) * DD + nf * 16 + l16] =
                        (oacc[qf][nf][r] + Of[row * 65 + nf * 16 + l16]) * inv;
            }
    }
}

extern "C" void kernel_launch(void* const* d_in, const int* in_sizes, int n_in,
                              void* d_out, int out_size, void* d_ws, size_t ws_size,
                              hipStream_t stream) {
    const float* Q = (const float*)d_in[0];
    const float* K = (const float*)d_in[1];
    const float* V = (const float*)d_in[2];
    const int*   M = (const int*)d_in[3];
    float*       O = (float*)d_out;

    unsigned short* Vt  = (unsigned short*)d_ws;                     // 6.29 MB
    unsigned short* Kb  = Vt + (size_t)BB * HH * SS * DD;            // 6.29 MB
    u64*            Mbt = (u64*)(Kb + (size_t)BB * HH * SS * DD);    // 1.05 MB

    prepass<<<dim3(BB * SS), 256, 0, stream>>>(V, K, M, Vt, Kb, Mbt);
    attn_fwd<<<dim3(SS / BQ, BB * HH), 512, 0, stream>>>(Q, Kb, Vt, Mbt, O);
}

// Round 8
// 171.805 us; speedup vs baseline: 1.0929x; 1.0929x over previous
//
#include <hip/hip_runtime.h>
#include <hip/hip_bf16.h>
#include <math.h>

// Flash attention, bf16 MFMA 16x16x32, fp32 accumulate. B=2,H=12,S=2048,D=64.
// R8: 32 q per wave (ratio: 20 ds_read_b128 per 36 MFMA) at high occupancy:
//  - GG=4 split-K -> 1536 blocks (6/CU); partials exactly additive (no-max exp)
//  - sacc liveness cut to 8 regs (QK->exp->P interleaved per 16-k frag)
//  - Ps halved to 32-k wave-private buffer (write half / read half, in-order
//    LDS per wave) -> 26.2 KB LDS/block -> 6 blocks/CU
// Staging: global_load_lds w=16 into XOR-swizzled LDS. S^T MFMA order (b64 P
// writes, coalesced transposed bit-mask). Row-sum l via ones-column MFMA.

#define BB 2
#define HH 12
#define SS 2048
#define DD 64
#define BQ 128
#define BK 64
#define GG 4
#define KG (SS / GG)      // 512 keys per group
#define NTG (KG / BK)     // 8 tiles per group
#define LPH 40            // Ps row stride in bf16 (80 B: 16B-aligned, 2-way banks)
#define LT 76             // prepass transpose stride
#define NROWS (BB * HH * SS)
#define QSCALE 0.1803368801111f   // 0.125 * log2(e)

typedef __attribute__((ext_vector_type(8))) short bf8_t;
typedef __attribute__((ext_vector_type(4))) short bf4_t;
typedef __attribute__((ext_vector_type(4))) float f4_t;
typedef unsigned long long u64;

__device__ __forceinline__ short f2bf(float f) {
    __hip_bfloat16 h = __float2bfloat16(f);
    return *reinterpret_cast<short*>(&h);
}

__device__ __forceinline__ void gl_lds16(const void* g, void* l) {
    __builtin_amdgcn_global_load_lds(
        (const __attribute__((address_space(1))) unsigned*)(g),
        (__attribute__((address_space(3))) unsigned*)(l), 16, 0, 0);
}

// swizzled tile: element (row, c8-chunk) lives at chunk row*8 + (c8 ^ (row&7))
__device__ __forceinline__ bf8_t ldfrag(const unsigned short* buf, int row, int c8) {
    return *(const bf8_t*)&buf[((row << 3) | (c8 ^ (row & 7))) << 3];
}

// ---------- fused prepass ----------
// grid = BB*SS = 4096 blocks x 256.
//  all blocks: pack mask row -> Mbt[b][word][row] (TRANSPOSED for coalescing)
//  bx <  768 : V [bh][s][d] fp32 -> Vt [bh][d][s] bf16 (64-row tile)
//  768..2304 : K fp32 -> Kb bf16
__global__ __launch_bounds__(256) void prepass(
    const float* __restrict__ V, const float* __restrict__ K,
    const int* __restrict__ M, unsigned short* __restrict__ Vt,
    unsigned short* __restrict__ Kb, u64* __restrict__ Mbt)
{
    __shared__ unsigned short Ts[64][LT];
    const int bx   = blockIdx.x;
    const int tid  = threadIdx.x;
    const int w    = tid >> 6;
    const int lane = tid & 63;
    const int b    = bx >> 11;
    const int row  = bx & 2047;

    {   // mask row bx -> 32 words, transposed layout [b][word][row]
        const int* src = M + (size_t)bx * SS;
        #pragma unroll
        for (int p = 0; p < 8; ++p) {
            int k = p * 256 + w * 64 + lane;
            u64 bm = __ballot(src[k] != 0);
            if (lane == 0)
                Mbt[(size_t)b * 32 * SS + (size_t)(p * 4 + w) * SS + row] = bm;
        }
    }

    if (bx < 768) {
        const int s0 = (bx & 31) * 64;
        const int bh = bx >> 5;
        const float* Vg = V + (size_t)bh * SS * DD;
        #pragma unroll
        for (int pass = 0; pass < 4; ++pass) {
            int c = tid + pass * 256;
            int r = c >> 4, col = (c & 15) * 4;
            float4 v = *(const float4*)(Vg + (size_t)(s0 + r) * DD + col);
            bf4_t p; p.x = f2bf(v.x); p.y = f2bf(v.y); p.z = f2bf(v.z); p.w = f2bf(v.w);
            *(bf4_t*)&Ts[r][col] = p;
        }
        __syncthreads();
        unsigned short* Vo = Vt + (size_t)bh * DD * SS;
        #pragma unroll
        for (int pass = 0; pass < 2; ++pass) {
            int c = tid + pass * 256;
            int d = c >> 3, sc = (c & 7) * 8;
            unsigned short t[8];
            #pragma unroll
            for (int u = 0; u < 8; ++u) t[u] = Ts[sc + u][d];
            uint4 o;
            o.x = (unsigned)t[0] | ((unsigned)t[1] << 16);
            o.y = (unsigned)t[2] | ((unsigned)t[3] << 16);
            o.z = (unsigned)t[4] | ((unsigned)t[5] << 16);
            o.w = (unsigned)t[6] | ((unsigned)t[7] << 16);
            *(uint4*)(Vo + (size_t)d * SS + s0 + sc) = o;
        }
    } else if (bx < 2304) {
        size_t i = ((size_t)(bx - 768) * 256 + tid) * 8;
        float4 a = *(const float4*)(K + i);
        float4 b2 = *(const float4*)(K + i + 4);
        uint4 o;
        o.x = (unsigned short)f2bf(a.x)  | ((unsigned)(unsigned short)f2bf(a.y)  << 16);
        o.y = (unsigned short)f2bf(a.z)  | ((unsigned)(unsigned short)f2bf(a.w)  << 16);
        o.z = (unsigned short)f2bf(b2.x) | ((unsigned)(unsigned short)f2bf(b2.y) << 16);
        o.w = (unsigned short)f2bf(b2.z) | ((unsigned)(unsigned short)f2bf(b2.w) << 16);
        *(uint4*)(Kb + i) = o;
    }
}

// ---------- main flash-attention kernel (partial over key group g) ----------
__global__ __launch_bounds__(256, 4) void attn_fwd(
    const float* __restrict__ Q, const unsigned short* __restrict__ Kb,
    const unsigned short* __restrict__ Vt, const u64* __restrict__ Mbt,
    float* __restrict__ Opart, float* __restrict__ Lpart)
{
    __shared__ unsigned short Ks[BK * DD];    // 8 KB, swizzled
    __shared__ unsigned short Vts[DD * BK];   // 8 KB, swizzled
    __shared__ unsigned short Ps[BQ * LPH];   // 10 KB, half-k, wave-private rows

    const int tid  = threadIdx.x;
    const int w    = tid >> 6;        // wave 0..3, owns q rows [w*32, w*32+32)
    const int lane = tid & 63;
    const int quad = lane >> 4;
    const int l16  = lane & 15;
    const int q0   = blockIdx.x * BQ;
    const int bh   = blockIdx.y;
    const int g    = blockIdx.z;
    const int b    = bh / HH;
    const int qbase = w * 32;

    const float*          Qg = Q  + (size_t)bh * SS * DD;
    const unsigned short* Kg = Kb + (size_t)bh * SS * DD;
    const unsigned short* Vg = Vt + (size_t)bh * DD * SS;
    float* Og = Opart + ((size_t)g * BB * HH + bh) * SS * DD;
    float* Lg = Lpart + (size_t)g * NROWS + (size_t)bh * SS;

    // ---- loop-invariant Q B-frags (two 16-row groups), 0.125*log2e folded
    bf8_t bq[2][2];
    #pragma unroll
    for (int qf = 0; qf < 2; ++qf)
        #pragma unroll
        for (int ks = 0; ks < 2; ++ks) {
            const float* qp = Qg + (size_t)(q0 + qbase + qf * 16 + l16) * DD
                                 + ks * 32 + quad * 8;
            float4 x = *(const float4*)qp;
            float4 y = *(const float4*)(qp + 4);
            bf8_t f;
            f[0] = f2bf(x.x * QSCALE); f[1] = f2bf(x.y * QSCALE);
            f[2] = f2bf(x.z * QSCALE); f[3] = f2bf(x.w * QSCALE);
            f[4] = f2bf(y.x * QSCALE); f[5] = f2bf(y.y * QSCALE);
            f[6] = f2bf(y.z * QSCALE); f[7] = f2bf(y.w * QSCALE);
            bq[qf][ks] = f;
        }

    // ---- ones column B-frag -> row-sum l in D col 0
    bf8_t onesf;
    {
        short ov = (l16 == 0) ? (short)0x3F80 : (short)0;
        #pragma unroll
        for (int j = 0; j < 8; ++j) onesf[j] = ov;
    }

    f4_t oacc[2][4], lacc[2];
    #pragma unroll
    for (int qf = 0; qf < 2; ++qf) {
        lacc[qf] = (f4_t){0.f, 0.f, 0.f, 0.f};
        #pragma unroll
        for (int nf = 0; nf < 4; ++nf) oacc[qf][nf] = (f4_t){0.f, 0.f, 0.f, 0.f};
    }

    // ---- strength-reduced staging pointers (4 gl_lds16 per wave per tile)
    const unsigned short* kSrc[2];
    const unsigned short* vSrc[2];
    unsigned short*       kDst[2];
    unsigned short*       vDst[2];
    #pragma unroll
    for (int j = 0; j < 2; ++j) {
        const int bc = (w * 2 + j) * 64;     // wave-uniform chunk base
        const int c  = bc + lane;
        const int r  = c >> 3;
        const int c8 = (c & 7) ^ (r & 7);
        kSrc[j] = Kg + (size_t)(g * KG + r) * DD + c8 * 8;
        vSrc[j] = Vg + (size_t)r * SS + g * KG + c8 * 8;
        kDst[j] = Ks  + bc * 8;
        vDst[j] = Vts + bc * 8;
    }
    const u64* mp[2];
    u64 mpf[2];
    #pragma unroll
    for (int qf = 0; qf < 2; ++qf) {
        mp[qf] = Mbt + (size_t)b * 32 * SS + (size_t)(g * NTG) * SS
                     + q0 + qbase + qf * 16 + l16;
        mpf[qf] = *mp[qf];
    }

    for (int t = 0; t < NTG; ++t) {
        __syncthreads();                 // prior tile's K/V LDS readers done
        #pragma unroll
        for (int j = 0; j < 2; ++j) {
            gl_lds16(kSrc[j], kDst[j]);
            gl_lds16(vSrc[j], vDst[j]);
            kSrc[j] += BK * DD;
            vSrc[j] += BK;
        }
        const u64 cm[2] = {mpf[0] >> (quad * 4), mpf[1] >> (quad * 4)};
        __syncthreads();                 // vmcnt drained: tiles visible
        if (t + 1 < NTG) {
            #pragma unroll
            for (int qf = 0; qf < 2; ++qf) {
                mp[qf] += SS;
                mpf[qf] = *mp[qf];       // flies during compute
            }
        }

        #pragma unroll
        for (int h = 0; h < 2; ++h) {
            // ---- QK^T + exp + P for this 32-k half (sacc live: 8 regs)
            #pragma unroll
            for (int kfh = 0; kfh < 2; ++kfh) {
                const int kf = h * 2 + kfh;
                bf8_t ak0 = ldfrag(Ks, kf * 16 + l16, quad);
                bf8_t ak1 = ldfrag(Ks, kf * 16 + l16, 4 + quad);
                #pragma unroll
                for (int qf = 0; qf < 2; ++qf) {
                    f4_t s = (f4_t){0.f, 0.f, 0.f, 0.f};
                    s = __builtin_amdgcn_mfma_f32_16x16x32_bf16(ak0, bq[qf][0], s, 0, 0, 0);
                    s = __builtin_amdgcn_mfma_f32_16x16x32_bf16(ak1, bq[qf][1], s, 0, 0, 0);
                    bf4_t pk;
                    #pragma unroll
                    for (int r = 0; r < 4; ++r) {
                        float e = exp2f(s[r]);
                        e = ((cm[qf] >> (kf * 16 + r)) & 1ull) ? e : 0.f;
                        pk[r] = f2bf(e);
                    }
                    *(bf4_t*)&Ps[(qbase + qf * 16 + l16) * LPH
                                 + kfh * 16 + quad * 4] = pk;
                }
            }
            // ---- P A-frags for the half (wave-private, in-order LDS)
            bf8_t ap[2];
            #pragma unroll
            for (int qf = 0; qf < 2; ++qf) {
                ap[qf] = *(const bf8_t*)&Ps[(qbase + qf * 16 + l16) * LPH
                                            + quad * 8];
                lacc[qf] = __builtin_amdgcn_mfma_f32_16x16x32_bf16(
                    ap[qf], onesf, lacc[qf], 0, 0, 0);
            }
            // ---- PV for the half; V frags shared across q-frags
            #pragma unroll
            for (int nf = 0; nf < 4; ++nf) {
                bf8_t bv = ldfrag(Vts, nf * 16 + l16, h * 4 + quad);
                #pragma unroll
                for (int qf = 0; qf < 2; ++qf)
                    oacc[qf][nf] = __builtin_amdgcn_mfma_f32_16x16x32_bf16(
                        ap[qf], bv, oacc[qf][nf], 0, 0, 0);
            }
        }
    }

    // ---- epilogue: store unnormalized O partial + l partial
    #pragma unroll
    for (int qf = 0; qf < 2; ++qf) {
        #pragma unroll
        for (int r = 0; r < 4; ++r) {
            const int row = q0 + qbase + qf * 16 + quad * 4 + r;
            #pragma unroll
            for (int nf = 0; nf < 4; ++nf)
                Og[(size_t)row * DD + nf * 16 + l16] = oacc[qf][nf][r];
        }
        if (l16 == 0) {
            #pragma unroll
            for (int r = 0; r < 4; ++r)
                Lg[q0 + qbase + qf * 16 + quad * 4 + r] = lacc[qf][r];
        }
    }
}

// ---------- reduce: O = (sum_g O_g) / (sum_g l_g) ----------
__global__ __launch_bounds__(256) void reduce_o(
    const float* __restrict__ Opart, const float* __restrict__ Lpart,
    float* __restrict__ O)
{
    const size_t idx = (size_t)blockIdx.x * 256 + threadIdx.x;  // float4 units
    const size_t row = idx >> 4;
    const int    c   = (int)(idx & 15) * 4;
    float4 acc = {0.f, 0.f, 0.f, 0.f};
    float  l   = 0.f;
    #pragma unroll
    for (int g = 0; g < GG; ++g) {
        float4 a = *(const float4*)(Opart + ((size_t)g * NROWS + row) * DD + c);
        acc.x += a.x; acc.y += a.y; acc.z += a.z; acc.w += a.w;
        l += Lpart[(size_t)g * NROWS + row];
    }
    const float inv = 1.f / l;
    float4 o;
    o.x = acc.x * inv; o.y = acc.y * inv; o.z = acc.z * inv; o.w = acc.w * inv;
    *(float4*)(O + row * DD + c) = o;
}

extern "C" void kernel_launch(void* const* d_in, const int* in_sizes, int n_in,
                              void* d_out, int out_size, void* d_ws, size_t ws_size,
                              hipStream_t stream) {
    const float* Q = (const float*)d_in[0];
    const float* K = (const float*)d_in[1];
    const float* V = (const float*)d_in[2];
    const int*   M = (const int*)d_in[3];
    float*       O = (float*)d_out;

    unsigned short* Vt    = (unsigned short*)d_ws;                   // 6.29 MB
    unsigned short* Kb    = Vt + (size_t)BB * HH * SS * DD;          // 6.29 MB
    u64*            Mbt   = (u64*)(Kb + (size_t)BB * HH * SS * DD);  // 1.05 MB
    float*          Opart = (float*)(Mbt + (size_t)BB * 32 * SS);    // 50.3 MB
    float*          Lpart = Opart + (size_t)GG * NROWS * DD;         // 0.79 MB

    prepass<<<dim3(BB * SS), 256, 0, stream>>>(V, K, M, Vt, Kb, Mbt);
    attn_fwd<<<dim3(SS / BQ, BB * HH, GG), 256, 0, stream>>>(Q, Kb, Vt, Mbt,
                                                             Opart, Lpart);
    reduce_o<<<dim3((NROWS * DD / 4) / 256), 256, 0, stream>>>(Opart, Lpart, O);
}

// Round 9
// 163.277 us; speedup vs baseline: 1.1499x; 1.0522x over previous
//
#include <hip/hip_runtime.h>
#include <hip/hip_bf16.h>
#include <math.h>

// Flash attention, bf16 MFMA 16x16x32, fp32 accumulate. B=2,H=12,S=2048,D=64.
// R9 = R8 + VALU diet on the 100M-element exp->P path:
//  - raw v_exp_f32 (__builtin_amdgcn_exp2f) instead of libm exp2f (~8x fewer)
//  - P bf16 conversion via v_perm_b32 truncation (1 instr / 2 elements);
//    truncation bias cancels in O = sum(P V)/sum(P) since l uses same P.
// Structure: GG=4 split-K (1536 blocks), 32 q/wave, global_load_lds w=16 into
// XOR-swizzled LDS, S^T MFMA order (b64 P writes, coalesced transposed
// bit-mask), row-sum l via ones-column MFMA, external reduce.

#define BB 2
#define HH 12
#define SS 2048
#define DD 64
#define BQ 128
#define BK 64
#define GG 4
#define KG (SS / GG)      // 512 keys per group
#define NTG (KG / BK)     // 8 tiles per group
#define LPH 40            // Ps row stride in bf16 (80 B: 16B-aligned, 2-way banks)
#define LT 76             // prepass transpose stride
#define NROWS (BB * HH * SS)
#define QSCALE 0.1803368801111f   // 0.125 * log2(e)

typedef __attribute__((ext_vector_type(8))) short bf8_t;
typedef __attribute__((ext_vector_type(4))) short bf4_t;
typedef __attribute__((ext_vector_type(4))) float f4_t;
typedef unsigned long long u64;

__device__ __forceinline__ short f2bf(float f) {
    __hip_bfloat16 h = __float2bfloat16(f);
    return *reinterpret_cast<short*>(&h);
}

__device__ __forceinline__ void gl_lds16(const void* g, void* l) {
    __builtin_amdgcn_global_load_lds(
        (const __attribute__((address_space(1))) unsigned*)(g),
        (__attribute__((address_space(3))) unsigned*)(l), 16, 0, 0);
}

// swizzled tile: element (row, c8-chunk) lives at chunk row*8 + (c8 ^ (row&7))
__device__ __forceinline__ bf8_t ldfrag(const unsigned short* buf, int row, int c8) {
    return *(const bf8_t*)&buf[((row << 3) | (c8 ^ (row & 7))) << 3];
}

// ---------- fused prepass ----------
// grid = BB*SS = 4096 blocks x 256.
//  all blocks: pack mask row -> Mbt[b][word][row] (TRANSPOSED for coalescing)
//  bx <  768 : V [bh][s][d] fp32 -> Vt [bh][d][s] bf16 (64-row tile)
//  768..2304 : K fp32 -> Kb bf16
__global__ __launch_bounds__(256) void prepass(
    const float* __restrict__ V, const float* __restrict__ K,
    const int* __restrict__ M, unsigned short* __restrict__ Vt,
    unsigned short* __restrict__ Kb, u64* __restrict__ Mbt)
{
    __shared__ unsigned short Ts[64][LT];
    const int bx   = blockIdx.x;
    const int tid  = threadIdx.x;
    const int w    = tid >> 6;
    const int lane = tid & 63;
    const int b    = bx >> 11;
    const int row  = bx & 2047;

    {   // mask row bx -> 32 words, transposed layout [b][word][row]
        const int* src = M + (size_t)bx * SS;
        #pragma unroll
        for (int p = 0; p < 8; ++p) {
            int k = p * 256 + w * 64 + lane;
            u64 bm = __ballot(src[k] != 0);
            if (lane == 0)
                Mbt[(size_t)b * 32 * SS + (size_t)(p * 4 + w) * SS + row] = bm;
        }
    }

    if (bx < 768) {
        const int s0 = (bx & 31) * 64;
        const int bh = bx >> 5;
        const float* Vg = V + (size_t)bh * SS * DD;
        #pragma unroll
        for (int pass = 0; pass < 4; ++pass) {
            int c = tid + pass * 256;
            int r = c >> 4, col = (c & 15) * 4;
            float4 v = *(const float4*)(Vg + (size_t)(s0 + r) * DD + col);
            bf4_t p; p.x = f2bf(v.x); p.y = f2bf(v.y); p.z = f2bf(v.z); p.w = f2bf(v.w);
            *(bf4_t*)&Ts[r][col] = p;
        }
        __syncthreads();
        unsigned short* Vo = Vt + (size_t)bh * DD * SS;
        #pragma unroll
        for (int pass = 0; pass < 2; ++pass) {
            int c = tid + pass * 256;
            int d = c >> 3, sc = (c & 7) * 8;
            unsigned short t[8];
            #pragma unroll
            for (int u = 0; u < 8; ++u) t[u] = Ts[sc + u][d];
            uint4 o;
            o.x = (unsigned)t[0] | ((unsigned)t[1] << 16);
            o.y = (unsigned)t[2] | ((unsigned)t[3] << 16);
            o.z = (unsigned)t[4] | ((unsigned)t[5] << 16);
            o.w = (unsigned)t[6] | ((unsigned)t[7] << 16);
            *(uint4*)(Vo + (size_t)d * SS + s0 + sc) = o;
        }
    } else if (bx < 2304) {
        size_t i = ((size_t)(bx - 768) * 256 + tid) * 8;
        float4 a = *(const float4*)(K + i);
        float4 b2 = *(const float4*)(K + i + 4);
        uint4 o;
        o.x = (unsigned short)f2bf(a.x)  | ((unsigned)(unsigned short)f2bf(a.y)  << 16);
        o.y = (unsigned short)f2bf(a.z)  | ((unsigned)(unsigned short)f2bf(a.w)  << 16);
        o.z = (unsigned short)f2bf(b2.x) | ((unsigned)(unsigned short)f2bf(b2.y) << 16);
        o.w = (unsigned short)f2bf(b2.z) | ((unsigned)(unsigned short)f2bf(b2.w) << 16);
        *(uint4*)(Kb + i) = o;
    }
}

// ---------- main flash-attention kernel (partial over key group g) ----------
__global__ __launch_bounds__(256, 4) void attn_fwd(
    const float* __restrict__ Q, const unsigned short* __restrict__ Kb,
    const unsigned short* __restrict__ Vt, const u64* __restrict__ Mbt,
    float* __restrict__ Opart, float* __restrict__ Lpart)
{
    __shared__ unsigned short Ks[BK * DD];    // 8 KB, swizzled
    __shared__ unsigned short Vts[DD * BK];   // 8 KB, swizzled
    __shared__ unsigned short Ps[BQ * LPH];   // 10 KB, half-k, wave-private rows

    const int tid  = threadIdx.x;
    const int w    = tid >> 6;        // wave 0..3, owns q rows [w*32, w*32+32)
    const int lane = tid & 63;
    const int quad = lane >> 4;
    const int l16  = lane & 15;
    const int q0   = blockIdx.x * BQ;
    const int bh   = blockIdx.y;
    const int g    = blockIdx.z;
    const int b    = bh / HH;
    const int qbase = w * 32;

    const float*          Qg = Q  + (size_t)bh * SS * DD;
    const unsigned short* Kg = Kb + (size_t)bh * SS * DD;
    const unsigned short* Vg = Vt + (size_t)bh * DD * SS;
    float* Og = Opart + ((size_t)g * BB * HH + bh) * SS * DD;
    float* Lg = Lpart + (size_t)g * NROWS + (size_t)bh * SS;

    // ---- loop-invariant Q B-frags (two 16-row groups), 0.125*log2e folded
    bf8_t bq[2][2];
    #pragma unroll
    for (int qf = 0; qf < 2; ++qf)
        #pragma unroll
        for (int ks = 0; ks < 2; ++ks) {
            const float* qp = Qg + (size_t)(q0 + qbase + qf * 16 + l16) * DD
                                 + ks * 32 + quad * 8;
            float4 x = *(const float4*)qp;
            float4 y = *(const float4*)(qp + 4);
            bf8_t f;
            f[0] = f2bf(x.x * QSCALE); f[1] = f2bf(x.y * QSCALE);
            f[2] = f2bf(x.z * QSCALE); f[3] = f2bf(x.w * QSCALE);
            f[4] = f2bf(y.x * QSCALE); f[5] = f2bf(y.y * QSCALE);
            f[6] = f2bf(y.z * QSCALE); f[7] = f2bf(y.w * QSCALE);
            bq[qf][ks] = f;
        }

    // ---- ones column B-frag -> row-sum l in D col 0
    bf8_t onesf;
    {
        short ov = (l16 == 0) ? (short)0x3F80 : (short)0;
        #pragma unroll
        for (int j = 0; j < 8; ++j) onesf[j] = ov;
    }

    f4_t oacc[2][4], lacc[2];
    #pragma unroll
    for (int qf = 0; qf < 2; ++qf) {
        lacc[qf] = (f4_t){0.f, 0.f, 0.f, 0.f};
        #pragma unroll
        for (int nf = 0; nf < 4; ++nf) oacc[qf][nf] = (f4_t){0.f, 0.f, 0.f, 0.f};
    }

    // ---- strength-reduced staging pointers (4 gl_lds16 per wave per tile)
    const unsigned short* kSrc[2];
    const unsigned short* vSrc[2];
    unsigned short*       kDst[2];
    unsigned short*       vDst[2];
    #pragma unroll
    for (int j = 0; j < 2; ++j) {
        const int bc = (w * 2 + j) * 64;     // wave-uniform chunk base
        const int c  = bc + lane;
        const int r  = c >> 3;
        const int c8 = (c & 7) ^ (r & 7);
        kSrc[j] = Kg + (size_t)(g * KG + r) * DD + c8 * 8;
        vSrc[j] = Vg + (size_t)r * SS + g * KG + c8 * 8;
        kDst[j] = Ks  + bc * 8;
        vDst[j] = Vts + bc * 8;
    }
    const u64* mp[2];
    u64 mpf[2];
    #pragma unroll
    for (int qf = 0; qf < 2; ++qf) {
        mp[qf] = Mbt + (size_t)b * 32 * SS + (size_t)(g * NTG) * SS
                     + q0 + qbase + qf * 16 + l16;
        mpf[qf] = *mp[qf];
    }

    for (int t = 0; t < NTG; ++t) {
        __syncthreads();                 // prior tile's K/V LDS readers done
        #pragma unroll
        for (int j = 0; j < 2; ++j) {
            gl_lds16(kSrc[j], kDst[j]);
            gl_lds16(vSrc[j], vDst[j]);
            kSrc[j] += BK * DD;
            vSrc[j] += BK;
        }
        const u64 cm[2] = {mpf[0] >> (quad * 4), mpf[1] >> (quad * 4)};
        __syncthreads();                 // vmcnt drained: tiles visible
        if (t + 1 < NTG) {
            #pragma unroll
            for (int qf = 0; qf < 2; ++qf) {
                mp[qf] += SS;
                mpf[qf] = *mp[qf];       // flies during compute
            }
        }

        #pragma unroll
        for (int h = 0; h < 2; ++h) {
            // ---- QK^T + exp + P for this 32-k half (sacc live: 8 regs)
            #pragma unroll
            for (int kfh = 0; kfh < 2; ++kfh) {
                const int kf = h * 2 + kfh;
                bf8_t ak0 = ldfrag(Ks, kf * 16 + l16, quad);
                bf8_t ak1 = ldfrag(Ks, kf * 16 + l16, 4 + quad);
                #pragma unroll
                for (int qf = 0; qf < 2; ++qf) {
                    f4_t s = (f4_t){0.f, 0.f, 0.f, 0.f};
                    s = __builtin_amdgcn_mfma_f32_16x16x32_bf16(ak0, bq[qf][0], s, 0, 0, 0);
                    s = __builtin_amdgcn_mfma_f32_16x16x32_bf16(ak1, bq[qf][1], s, 0, 0, 0);
                    // raw v_exp_f32 + mask zero + v_perm truncate-pack
                    float e[4];
                    #pragma unroll
                    for (int r = 0; r < 4; ++r) {
                        float v = __builtin_amdgcn_exp2f(s[r]);
                        e[r] = ((cm[qf] >> (kf * 16 + r)) & 1ull) ? v : 0.f;
                    }
                    uint2 pw;
                    pw.x = __builtin_amdgcn_perm(__float_as_uint(e[1]),
                                                 __float_as_uint(e[0]),
                                                 0x07060302u);
                    pw.y = __builtin_amdgcn_perm(__float_as_uint(e[3]),
                                                 __float_as_uint(e[2]),
                                                 0x07060302u);
                    *(uint2*)&Ps[(qbase + qf * 16 + l16) * LPH
                                 + kfh * 16 + quad * 4] = pw;
                }
            }
            // ---- P A-frags for the half (wave-private, in-order LDS)
            bf8_t ap[2];
            #pragma unroll
            for (int qf = 0; qf < 2; ++qf) {
                ap[qf] = *(const bf8_t*)&Ps[(qbase + qf * 16 + l16) * LPH
                                            + quad * 8];
                lacc[qf] = __builtin_amdgcn_mfma_f32_16x16x32_bf16(
                    ap[qf], onesf, lacc[qf], 0, 0, 0);
            }
            // ---- PV for the half; V frags shared across q-frags
            #pragma unroll
            for (int nf = 0; nf < 4; ++nf) {
                bf8_t bv = ldfrag(Vts, nf * 16 + l16, h * 4 + quad);
                #pragma unroll
                for (int qf = 0; qf < 2; ++qf)
                    oacc[qf][nf] = __builtin_amdgcn_mfma_f32_16x16x32_bf16(
                        ap[qf], bv, oacc[qf][nf], 0, 0, 0);
            }
        }
    }

    // ---- epilogue: store unnormalized O partial + l partial
    #pragma unroll
    for (int qf = 0; qf < 2; ++qf) {
        #pragma unroll
        for (int r = 0; r < 4; ++r) {
            const int row = q0 + qbase + qf * 16 + quad * 4 + r;
            #pragma unroll
            for (int nf = 0; nf < 4; ++nf)
                Og[(size_t)row * DD + nf * 16 + l16] = oacc[qf][nf][r];
        }
        if (l16 == 0) {
            #pragma unroll
            for (int r = 0; r < 4; ++r)
                Lg[q0 + qbase + qf * 16 + quad * 4 + r] = lacc[qf][r];
        }
    }
}

// ---------- reduce: O = (sum_g O_g) / (sum_g l_g) ----------
__global__ __launch_bounds__(256) void reduce_o(
    const float* __restrict__ Opart, const float* __restrict__ Lpart,
    float* __restrict__ O)
{
    const size_t idx = (size_t)blockIdx.x * 256 + threadIdx.x;  // float4 units
    const size_t row = idx >> 4;
    const int    c   = (int)(idx & 15) * 4;
    float4 acc = {0.f, 0.f, 0.f, 0.f};
    float  l   = 0.f;
    #pragma unroll
    for (int g = 0; g < GG; ++g) {
        float4 a = *(const float4*)(Opart + ((size_t)g * NROWS + row) * DD + c);
        acc.x += a.x; acc.y += a.y; acc.z += a.z; acc.w += a.w;
        l += Lpart[(size_t)g * NROWS + row];
    }
    const float inv = 1.f / l;
    float4 o;
    o.x = acc.x * inv; o.y = acc.y * inv; o.z = acc.z * inv; o.w = acc.w * inv;
    *(float4*)(O + row * DD + c) = o;
}

extern "C" void kernel_launch(void* const* d_in, const int* in_sizes, int n_in,
                              void* d_out, int out_size, void* d_ws, size_t ws_size,
                              hipStream_t stream) {
    const float* Q = (const float*)d_in[0];
    const float* K = (const float*)d_in[1];
    const float* V = (const float*)d_in[2];
    const int*   M = (const int*)d_in[3];
    float*       O = (float*)d_out;

    unsigned short* Vt    = (unsigned short*)d_ws;                   // 6.29 MB
    unsigned short* Kb    = Vt + (size_t)BB * HH * SS * DD;          // 6.29 MB
    u64*            Mbt   = (u64*)(Kb + (size_t)BB * HH * SS * DD);  // 1.05 MB
    float*          Opart = (float*)(Mbt + (size_t)BB * 32 * SS);    // 50.3 MB
    float*          Lpart = Opart + (size_t)GG * NROWS * DD;         // 0.79 MB

    prepass<<<dim3(BB * SS), 256, 0, stream>>>(V, K, M, Vt, Kb, Mbt);
    attn_fwd<<<dim3(SS / BQ, BB * HH, GG), 256, 0, stream>>>(Q, Kb, Vt, Mbt,
                                                             Opart, Lpart);
    reduce_o<<<dim3((NROWS * DD / 4) / 256), 256, 0, stream>>>(Opart, Lpart, O);
}